// Round 3
// baseline (263.023 us; speedup 1.0000x reference)
//
#include <hip/hip_runtime.h>

// Problem constants
#define BATCH 4096
#define INF   2048
#define OUTF  2048

typedef __attribute__((ext_vector_type(8))) short bf16x8;
typedef __attribute__((ext_vector_type(4))) float f32x4;

// float -> bf16 bits, round-to-nearest-even
__device__ inline unsigned short f2bf(float f) {
  unsigned int u = __float_as_uint(f);
  u += 0x7fffu + ((u >> 16) & 1u);
  return (unsigned short)(u >> 16);
}

// 16B async global->LDS. LDS dest is wave-uniform base; HW writes base + lane*16.
__device__ inline void gld16(const void* g, void* l) {
  __builtin_amdgcn_global_load_lds(
      (const __attribute__((address_space(1))) void*)g,
      (__attribute__((address_space(3))) void*)l,
      16, 0, 0);
}

// Fused pack: x_re,x_im (4096x2048) and w_re,w_im (2048x2048) fp32 -> bf16 row-major.
__global__ __launch_bounds__(256) void pack_all(const float* __restrict__ xr,
                                                const float* __restrict__ xi,
                                                const float* __restrict__ wr,
                                                const float* __restrict__ wi,
                                                unsigned short* __restrict__ Xre,
                                                unsigned short* __restrict__ Xim,
                                                unsigned short* __restrict__ Wr,
                                                unsigned short* __restrict__ Wi) {
  const int XCH = (BATCH * INF) / 8;
  int t = blockIdx.x * 256 + threadIdx.x;
  const float4 *s0, *s1;
  bf16x8 *d0, *d1;
  int idx;
  if (t < XCH) {
    idx = t;
    s0 = (const float4*)xr; s1 = (const float4*)xi;
    d0 = (bf16x8*)Xre;      d1 = (bf16x8*)Xim;
  } else {
    idx = t - XCH;
    s0 = (const float4*)wr; s1 = (const float4*)wi;
    d0 = (bf16x8*)Wr;       d1 = (bf16x8*)Wi;
  }
  float4 a0 = s0[2 * idx], a1 = s0[2 * idx + 1];
  float4 b0 = s1[2 * idx], b1 = s1[2 * idx + 1];
  bf16x8 v0, v1;
  v0[0] = (short)f2bf(a0.x); v0[1] = (short)f2bf(a0.y);
  v0[2] = (short)f2bf(a0.z); v0[3] = (short)f2bf(a0.w);
  v0[4] = (short)f2bf(a1.x); v0[5] = (short)f2bf(a1.y);
  v0[6] = (short)f2bf(a1.z); v0[7] = (short)f2bf(a1.w);
  v1[0] = (short)f2bf(b0.x); v1[1] = (short)f2bf(b0.y);
  v1[2] = (short)f2bf(b0.z); v1[3] = (short)f2bf(b0.w);
  v1[4] = (short)f2bf(b1.x); v1[5] = (short)f2bf(b1.y);
  v1[6] = (short)f2bf(b1.z); v1[7] = (short)f2bf(b1.w);
  d0[idx] = v0;
  d1[idx] = v1;
}

// Fused complex GEMM, double-buffered async staging.
// out[b,o,0] = Xre.Wr^T - Xim.Wi^T ; out[b,o,1] = Xre.Wi^T + Xim.Wr^T
// 128x128 block tile, 4 waves (2x2), each 64x64 via 4x4 mfma 16x16x32 bf16.
// BK=32, two LDS buffers per array (4 arrays x 16 KB = 64 KB), 2 blocks/CU.
// Per iter: issue gld16 prefetch into buf p^1, compute buf p (64 MFMA), barrier.
// The barrier's vmcnt drain overlaps the whole compute phase -> cheap.
__global__ __launch_bounds__(256, 2) void cgemm(const unsigned short* __restrict__ Xre,
                                                const unsigned short* __restrict__ Xim,
                                                const unsigned short* __restrict__ Wr,
                                                const unsigned short* __restrict__ Wi,
                                                float* __restrict__ out) {
  __shared__ unsigned short sXre[2 * 4096];  // [buf][128x32], 16 KB each array
  __shared__ unsigned short sXim[2 * 4096];
  __shared__ unsigned short sWr[2 * 4096];
  __shared__ unsigned short sWi[2 * 4096];

  const int tid  = threadIdx.x;
  const int wid  = tid >> 6;
  const int lane = tid & 63;
  const int lrow = lane & 15;
  const int lhi  = lane >> 4;
  const int wm   = wid >> 1;
  const int wn   = wid & 1;

  const int bn0 = blockIdx.x * 128;   // out-feature tile
  const int bm0 = blockIdx.y * 128;   // batch tile

  // Staging map: chunk ch = p*256+tid -> LDS(row=ch>>2, c=ch&3); source column
  // chunk swizzled so LDS(r,c) holds global chunk c^s(r), s(r)=(r&3)^((r>>2)&3).
  const int srow = tid >> 2;
  const int sc   = tid & 3;
  const int ss   = (srow & 3) ^ ((srow >> 2) & 3);
  const int scol = (sc ^ ss) * 8;     // shorts within the 32-wide tile

  const unsigned short* gXre = Xre + (size_t)(bm0 + srow) * INF + scol;
  const unsigned short* gXim = Xim + (size_t)(bm0 + srow) * INF + scol;
  const unsigned short* gWr  = Wr  + (size_t)(bn0 + srow) * INF + scol;
  const unsigned short* gWi  = Wi  + (size_t)(bn0 + srow) * INF + scol;

  const int ldsoff = wid * 1024;      // bytes within one 8 KB buffer

  // Fragment read: logical k-chunk lhi -> LDS chunk lhi^s(row); rows differ by
  // multiples of 16 so s(row) == s(lrow) for all i.
  const int slane  = (lrow & 3) ^ ((lrow >> 2) & 3);
  const int kchunk = (lhi ^ slane) * 8;   // shorts

  f32x4 accre[4][4], accim[4][4];
  const f32x4 zz = {0.f, 0.f, 0.f, 0.f};
#pragma unroll
  for (int i = 0; i < 4; ++i)
#pragma unroll
    for (int j = 0; j < 4; ++j) { accre[i][j] = zz; accim[i][j] = zz; }

  const bf16x8 SGN = {(short)0x8000, (short)0x8000, (short)0x8000, (short)0x8000,
                      (short)0x8000, (short)0x8000, (short)0x8000, (short)0x8000};

  // Stage one 128x32 tile of all 4 arrays into buffer b at k-offset go.
#define STAGE(b, go)                                                          \
  do {                                                                        \
    const int lo = (b) * 8192 + ldsoff;                                       \
    gld16(gXre + (go),                    (char*)sXre + lo);                  \
    gld16(gXre + (go) + (size_t)64 * INF, (char*)sXre + lo + 4096);           \
    gld16(gXim + (go),                    (char*)sXim + lo);                  \
    gld16(gXim + (go) + (size_t)64 * INF, (char*)sXim + lo + 4096);           \
    gld16(gWr + (go),                     (char*)sWr + lo);                   \
    gld16(gWr + (go) + (size_t)64 * INF,  (char*)sWr + lo + 4096);            \
    gld16(gWi + (go),                     (char*)sWi + lo);                   \
    gld16(gWi + (go) + (size_t)64 * INF,  (char*)sWi + lo + 4096);            \
  } while (0)

  // Compute one BK=32 step from buffer b.
#define COMPUTE(b)                                                            \
  do {                                                                        \
    const int hb = (b) * 4096;  /* shorts */                                  \
    bf16x8 xr_[4], xi_[4], wr_[4], wi_[4], wn_[4];                            \
    _Pragma("unroll")                                                         \
    for (int i = 0; i < 4; ++i) {                                             \
      xr_[i] = *(const bf16x8*)&sXre[hb + (wm * 64 + i * 16 + lrow) * 32 + kchunk]; \
      xi_[i] = *(const bf16x8*)&sXim[hb + (wm * 64 + i * 16 + lrow) * 32 + kchunk]; \
      wr_[i] = *(const bf16x8*)&sWr [hb + (wn * 64 + i * 16 + lrow) * 32 + kchunk]; \
      wi_[i] = *(const bf16x8*)&sWi [hb + (wn * 64 + i * 16 + lrow) * 32 + kchunk]; \
    }                                                                         \
    _Pragma("unroll")                                                         \
    for (int j = 0; j < 4; ++j) wn_[j] = wi_[j] ^ SGN;                        \
    _Pragma("unroll")                                                         \
    for (int i = 0; i < 4; ++i)                                               \
      _Pragma("unroll")                                                       \
      for (int j = 0; j < 4; ++j) {                                           \
        accre[i][j] = __builtin_amdgcn_mfma_f32_16x16x32_bf16(xr_[i], wr_[j], accre[i][j], 0, 0, 0); \
        accre[i][j] = __builtin_amdgcn_mfma_f32_16x16x32_bf16(xi_[i], wn_[j], accre[i][j], 0, 0, 0); \
        accim[i][j] = __builtin_amdgcn_mfma_f32_16x16x32_bf16(xr_[i], wi_[j], accim[i][j], 0, 0, 0); \
        accim[i][j] = __builtin_amdgcn_mfma_f32_16x16x32_bf16(xi_[i], wr_[j], accim[i][j], 0, 0, 0); \
      }                                                                       \
  } while (0)

  // Prologue: fill buffer 0 with k=[0,32)
  STAGE(0, 0);
  __syncthreads();

  for (int kt = 0; kt < INF; kt += 64) {
    // even half: prefetch buf1 <- kt+32, compute buf0 (data kt)
    STAGE(1, kt + 32);
    COMPUTE(0);
    __syncthreads();   // waves done with buf0; drains prefetch (overlapped)
    // odd half: prefetch buf0 <- kt+64, compute buf1 (data kt+32)
    if (kt + 64 < INF) STAGE(0, kt + 64);
    COMPUTE(1);
    __syncthreads();
  }

  // Epilogue: C/D layout col=lane&15, row=(lane>>4)*4+reg. Interleaved {re,im}.
  const int row0 = bm0 + wm * 64 + lhi * 4;
  const int col0 = bn0 + wn * 64 + lrow;
#pragma unroll
  for (int i = 0; i < 4; ++i)
#pragma unroll
    for (int j = 0; j < 4; ++j)
#pragma unroll
      for (int r = 0; r < 4; ++r) {
        int row = row0 + i * 16 + r;
        int col = col0 + j * 16;
        float2 v = make_float2(accre[i][j][r], accim[i][j][r]);
        *(float2*)&out[((size_t)row * OUTF + col) * 2] = v;
      }
#undef STAGE
#undef COMPUTE
}

// Safety fallback if workspace too small: fp32 vector path (slow but correct)
__global__ __launch_bounds__(256) void naive_cx(const float* __restrict__ xr,
                                                const float* __restrict__ xi,
                                                const float* __restrict__ wr,
                                                const float* __restrict__ wi,
                                                float* __restrict__ out) {
  int t = blockIdx.x * 256 + threadIdx.x;
  int b = t >> 11, o = t & 2047;
  const float* xrb = xr + (size_t)b * INF;
  const float* xib = xi + (size_t)b * INF;
  const float* wrb = wr + (size_t)o * INF;
  const float* wib = wi + (size_t)o * INF;
  float are = 0.f, aim = 0.f;
  for (int i = 0; i < INF; ++i) {
    float a = xrb[i], c = xib[i], p = wrb[i], q = wib[i];
    are += a * p - c * q;
    aim += a * q + c * p;
  }
  out[(size_t)t * 2 + 0] = are;
  out[(size_t)t * 2 + 1] = aim;
}

extern "C" void kernel_launch(void* const* d_in, const int* in_sizes, int n_in,
                              void* d_out, int out_size, void* d_ws, size_t ws_size,
                              hipStream_t stream) {
  const float* xr = (const float*)d_in[0];
  const float* xi = (const float*)d_in[1];
  const float* wr = (const float*)d_in[2];
  const float* wi = (const float*)d_in[3];
  float* out = (float*)d_out;

  const size_t nx = (size_t)BATCH * INF;
  const size_t nw = (size_t)OUTF * INF;
  const size_t need = (2 * nx + 2 * nw) * sizeof(unsigned short);  // 48 MiB

  if (ws_size < need) {
    naive_cx<<<(BATCH * OUTF) / 256, 256, 0, stream>>>(xr, xi, wr, wi, out);
    return;
  }

  unsigned short* Xre = (unsigned short*)d_ws;
  unsigned short* Xim = Xre + nx;
  unsigned short* Wr  = Xim + nx;
  unsigned short* Wi  = Wr + nw;

  const int grid_pack = (int)((nx / 8 + nw / 8) / 256);  // 6144
  pack_all<<<grid_pack, 256, 0, stream>>>(xr, xi, wr, wi, Xre, Xim, Wr, Wi);

  dim3 grid(OUTF / 128, BATCH / 128);  // 16 x 32 = 512 blocks
  cgemm<<<grid, 256, 0, stream>>>(Xre, Xim, Wr, Wi, out);
}